// Round 21
// baseline (420.540 us; speedup 1.0000x reference)
//
#include <hip/hip_runtime.h>
#include <hip/hip_bf16.h>
#include <hip/hip_fp16.h>

typedef __hip_bfloat16 bf16;
typedef unsigned short u16;
typedef short bfrag __attribute__((ext_vector_type(8)));   // 8 bf16 = 4 VGPRs
typedef float f32x4 __attribute__((ext_vector_type(4)));
typedef unsigned u32x2 __attribute__((ext_vector_type(2))); // native vec for nt-store

#define NGRAPH 512
#define BN_EPS 1e-5f
#define NBUCK 64

__device__ __forceinline__ float b2f(bf16 x) { return __bfloat162float(x); }
__device__ __forceinline__ float bf_lo(unsigned u) { return __uint_as_float(u << 16); }
__device__ __forceinline__ float bf_hi(unsigned u) { return __uint_as_float(u & 0xffff0000u); }
__device__ __forceinline__ u16 f2u(float v) {
    bf16 t = __float2bfloat16(v);
    u16 r; __builtin_memcpy(&r, &t, 2); return r;
}

__device__ __forceinline__ float load_f(const void* p, int i, int isbf16) {
    if (isbf16) {
        unsigned short u = ((const unsigned short*)p)[i];
        return __uint_as_float(((unsigned int)u) << 16);
    }
    return ((const float*)p)[i];
}

// ---------------- fused prep+init ----------------
__device__ __forceinline__ void repack_sec(const void* W, u16* out, int Kd, int Nd,
                                           int t, int isbf) {
    if (t >= Kd * Nd) return;
    int j = t & 7;
    int lane = (t >> 3) & 63;
    int tile = t >> 9;
    int NT = Nd / 16;
    int nt = tile % NT, kt = tile / NT;
    int k = kt * 32 + (lane >> 4) * 8 + j;
    int nn = nt * 16 + (lane & 15);
    out[t] = f2u(load_f(W, k * Nd + nn, isbf));
}

__device__ __forceinline__ void fold_one(const void* b, const void* g, const void* be,
                                         const void* m, const void* v,
                                         float* S, float* T, int f, int isbf) {
    float bb = load_f(b, f, isbf), gg = load_f(g, f, isbf);
    float bee = load_f(be, f, isbf), mm = load_f(m, f, isbf);
    float vv = load_f(v, f, isbf);
    float s = gg * rsqrtf(vv + BN_EPS);
    S[f] = s;
    T[f] = (bb - mm) * s + bee;
}

__global__ void prep_all(
    const void* __restrict__ x,
    const void* W1, const void* W2, const void* W3,
    const void* b1, const void* g1, const void* be1, const void* m1, const void* v1,
    const void* b2, const void* g2, const void* be2, const void* m2, const void* v2,
    const void* b3, const void* g3, const void* be3, const void* m3, const void* v3,
    u16* __restrict__ xs, u16* W1r, u16* W2r, u16* W3r,
    float* S1, float* T1, float* S2, float* T2, float* S3, float* T3,
    int* __restrict__ deg, int* __restrict__ ovf, int* __restrict__ bcnt,
    int* __restrict__ claim, float* __restrict__ psum, float* __restrict__ pmax,
    int* __restrict__ pcnt,
    int n, int npad, int* __restrict__ flag) {
    __shared__ int lflag;
    if (threadIdx.x < 64) {
        unsigned short u = ((const unsigned short*)x)[2 * threadIdx.x];
        float f = __uint_as_float(((unsigned int)u) << 16);
        int crazy = (!(fabsf(f) <= 1024.0f)) ? 1 : 0;
        unsigned long long m = __ballot(crazy);
        if (threadIdx.x == 0) lflag = (m == 0ULL) ? 1 : 0;
    }
    __syncthreads();
    const int isbf = lflag;
    const int bid = blockIdx.x;
    const int tid = threadIdx.x;
    if (bid == 0 && tid == 0) *flag = isbf;

    const int nb_cvt = (n * 64 + 255) / 256;
    if (bid < nb_cvt) {
        int i = bid * 256 + tid;
        if (i < n * 64) {
            int node = i >> 6, f = i & 63;
            xs[((size_t)(f >> 5) * npad + node) * 32 + (f & 31)] = f2u(load_f(x, i, isbf));
        }
        return;
    }
    int b2_ = bid - nb_cvt;
    if (b2_ < 32)  { repack_sec(W1, W1r, 64, 128, b2_ * 256 + tid, isbf); return; }
    b2_ -= 32;
    if (b2_ < 128) { repack_sec(W2, W2r, 128, 256, b2_ * 256 + tid, isbf); return; }
    b2_ -= 128;
    if (b2_ < 256) { repack_sec(W3, W3r, 256, 256, b2_ * 256 + tid, isbf); return; }
    b2_ -= 256;
    if (b2_ < 3) {
        int t = b2_ * 256 + tid;
        if (t < 128) fold_one(b1, g1, be1, m1, v1, S1, T1, t, isbf);
        else if (t < 384) fold_one(b2, g2, be2, m2, v2, S2, T2, t - 128, isbf);
        else if (t < 640) fold_one(b3, g3, be3, m3, v3, S3, T3, t - 384, isbf);
        return;
    }
    b2_ -= 3;
    {
        int i = b2_ * 256 + tid;
        if (i < n) deg[i] = 0;
        if (i < NGRAPH * 256) { psum[i] = 0.f; pmax[i] = 0.f; }
        if (i < NGRAPH) pcnt[i] = 0;
        if (i < NBUCK) { bcnt[i] = 0; claim[i] = 0; }
        if (i == 0) *ovf = 0;
    }
}

__global__ void count_deg_i(const int* __restrict__ dst, int* __restrict__ deg, int e) {
    int i = blockIdx.x * blockDim.x + threadIdx.x;
    if (i < e) atomicAdd(&deg[dst[i]], 1);
}

// Histogram by dpad-bucket k=(deg+7)>>3 + dis. LDS hist (r9 lesson).
__global__ void hist_rows(const int* __restrict__ deg, float* __restrict__ dis,
                          int* __restrict__ bcnt, int n) {
    __shared__ int lh[NBUCK];
    int tid = threadIdx.x;
    if (tid < NBUCK) lh[tid] = 0;
    __syncthreads();
    int i = blockIdx.x * blockDim.x + tid;
    if (i < n) {
        int d = deg[i];
        dis[i] = rsqrtf((float)(d + 1));    // +1 self-loop
        atomicAdd(&lh[min((d + 7) >> 3, NBUCK - 1)], 1);
    }
    __syncthreads();
    if (tid < NBUCK) {
        int c = lh[tid];
        if (c) atomicAdd(&bcnt[tid], c);
    }
}

// Node scatter: sorted rank -> closed-form csrw start so csrw order matches
// ninfo processing order (sequential segment walks; r20: FETCH 61->34 MB).
__global__ void node_scatter(const int* __restrict__ deg, const int* __restrict__ bcnt,
                             int* __restrict__ claim, int* __restrict__ ovf,
                             int* __restrict__ cursor, unsigned* __restrict__ csrw,
                             uint4* __restrict__ ninfo, int n, int cap) {
    __shared__ int lh[NBUCK];
    __shared__ int lbase[NBUCK];
    __shared__ int cpre[NBUCK];
    __shared__ int wpre[NBUCK];
    int tid = threadIdx.x;
    if (tid < NBUCK) lh[tid] = 0;
    if (tid == 64) {
        int ca = 0, wa = 0;
        for (int k = 0; k < NBUCK; k++) {
            cpre[k] = ca; wpre[k] = wa;
            ca += bcnt[k]; wa += bcnt[k] * 8 * k;
        }
    }
    __syncthreads();
    int i = blockIdx.x * blockDim.x + tid;
    int b = 0, lr = 0, d = 0;
    if (i < n) {
        d = deg[i];
        b = min((d + 7) >> 3, NBUCK - 1);
        lr = atomicAdd(&lh[b], 1);
    }
    __syncthreads();
    if (tid < NBUCK) {
        int c = lh[tid];
        lbase[tid] = c ? atomicAdd(&claim[tid], c) : 0;
    }
    __syncthreads();
    if (i >= n) return;
    int rank = lbase[b] + lr;
    int pos = cpre[b] + rank;
    int dpad = (d + 7) & ~7;
    int start;
    if (b < NBUCK - 1) {
        start = wpre[b] + rank * 8 * b;
    } else {
        start = cap - atomicAdd(ovf, dpad) - dpad;
    }
    cursor[i] = start;
    unsigned val = (unsigned)(i & 0xffff);   // pad: src=self, norm=+0
    for (int k = d; k < dpad; k++) csrw[start + k] = val;
    ninfo[pos] = make_uint4(i, start, d, 0);
}

__global__ void edge_scatter(const int* __restrict__ src, const int* __restrict__ dst,
                             const float* __restrict__ dis, int* __restrict__ cursor,
                             unsigned* __restrict__ csrw, int e) {
    int i = blockIdx.x * blockDim.x + threadIdx.x;
    if (i >= e) return;
    int s = src[i], dt = dst[i];
    int pos = atomicAdd(&cursor[dt], 1);
    float nw = dis[s] * dis[dt];
    unsigned short h = __half_as_ushort(__float2half(nw));
    csrw[pos] = (unsigned)(s & 0xffff) | ((unsigned)h << 16);
}

// ---------------- XCD-sliced CSR aggregation v6: 16-deep gather pipeline ---
// r20: agg is latency-bound (hbm 15%, VALU 48%, L2 agg ~8/34 TB/s). Doubling
// outstanding gathers per wave (8 -> 16 in flight) attacks the latency bound.
// Deg-buckets keep trip counts wave-uniform; dpad % 8 == 0 -> one 8-wide tail.
template <int NSLICE>
__global__ __launch_bounds__(256) void csr_agg_s6(
    const uint4* __restrict__ ninfo, const unsigned* __restrict__ csrw,
    const u16* __restrict__ hs, u16* __restrict__ AG, int n, int npad) {
    constexpr int F = NSLICE * 32;
    int slice = blockIdx.x % NSLICE;
    int nb = blockIdx.x / NSLICE;
    int lane = threadIdx.x & 63;
    int wv = threadIdx.x >> 6;
    int sub = lane >> 3, ls = lane & 7;
    int oidx = nb * 32 + wv * 8 + sub;
    if (oidx >= n) return;
    uint4 nf = ninfo[oidx];
    int node = (int)nf.x;
    int start = (int)nf.y;
    int d = (int)nf.z;
    int dpad = (d + 7) & ~7;
    float dd = 1.0f / (float)(d + 1);
    const u16* __restrict__ base = hs + (size_t)slice * npad * 32;

    float a0, a1, a2, a3;
    {
        uint2 u = *(const uint2*)(base + (size_t)node * 32 + ls * 4);
        a0 = bf_lo(u.x) * dd; a1 = bf_hi(u.x) * dd;
        a2 = bf_lo(u.y) * dd; a3 = bf_hi(u.y) * dd;
    }

    const unsigned* __restrict__ ep = csrw + start;
    int k = 0;
    for (; k + 16 <= dpad; k += 16) {
        unsigned m[16];
#pragma unroll
        for (int j = 0; j < 16; j++) m[j] = ep[k + j];   // sequential, L2-hit
        uint2 q[16];
#pragma unroll
        for (int j = 0; j < 16; j++) {
            int s = (int)(m[j] & 0xffffu);
            q[j] = *(const uint2*)(base + (size_t)s * 32 + ls * 4);  // 16 in flight
        }
#pragma unroll
        for (int j = 0; j < 16; j++) {
            float w = __half2float(__ushort_as_half((unsigned short)(m[j] >> 16)));
            a0 += w * bf_lo(q[j].x); a1 += w * bf_hi(q[j].x);
            a2 += w * bf_lo(q[j].y); a3 += w * bf_hi(q[j].y);
        }
    }
    if (k < dpad) {   // 8-wide tail (dpad % 16 == 8)
        unsigned m[8];
#pragma unroll
        for (int j = 0; j < 8; j++) m[j] = ep[k + j];
        uint2 q[8];
#pragma unroll
        for (int j = 0; j < 8; j++) {
            int s = (int)(m[j] & 0xffffu);
            q[j] = *(const uint2*)(base + (size_t)s * 32 + ls * 4);
        }
#pragma unroll
        for (int j = 0; j < 8; j++) {
            float w = __half2float(__ushort_as_half((unsigned short)(m[j] >> 16)));
            a0 += w * bf_lo(q[j].x); a1 += w * bf_hi(q[j].x);
            a2 += w * bf_lo(q[j].y); a3 += w * bf_hi(q[j].y);
        }
    }
    u32x2 o;
    o.x = (unsigned)f2u(a0) | ((unsigned)f2u(a1) << 16);
    o.y = (unsigned)f2u(a2) | ((unsigned)f2u(a3) << 16);
    __builtin_nontemporal_store(o, (u32x2*)(AG + (size_t)node * F + slice * 32 + ls * 4));
}

// ---------------- LDS-free direct-gather MFMA GEMM + fused BN + ReLU -------
template <int K, int N, int NSUB, int NSLICE_OUT>
__global__ __launch_bounds__(256) void mfma_gemm_dg(
    const u16* __restrict__ A, const u16* __restrict__ Wrep,
    const float* __restrict__ S, const float* __restrict__ T,
    u16* __restrict__ C, int M, int npad, int ntiles) {
    constexpr int NT = N / 16;
    constexpr int KT = K / 32;
    constexpr int NSPLIT = NT / NSUB;
    int bid = blockIdx.x;
    int g = bid >> 3;
    int ns = g % NSPLIT;
    int mt = (bid & 7) + 8 * (g / NSPLIT);
    if (mt >= ntiles) return;
    const int tid = threadIdx.x;
    const int lane = tid & 63;
    const int wv = tid >> 6;
    const int mrow = lane & 15;
    const int kb = lane >> 4;

    bfrag breg[KT * NSUB];
#pragma unroll
    for (int kt = 0; kt < KT; kt++)
#pragma unroll
        for (int j = 0; j < NSUB; j++)
            breg[kt * NSUB + j] = *(const bfrag*)(Wrep +
                ((size_t)(kt * NT + ns * NSUB + j) * 64 + lane) * 8);

    const u16* __restrict__ arow = A + (size_t)(mt * 64 + wv * 16 + mrow) * K + kb * 8;
    bfrag areg[KT];
#pragma unroll
    for (int kt = 0; kt < KT; kt++)
        areg[kt] = *(const bfrag*)(arow + kt * 32);

    f32x4 acc[NSUB];
#pragma unroll
    for (int j = 0; j < NSUB; j++) acc[j] = (f32x4){0.f, 0.f, 0.f, 0.f};
#pragma unroll
    for (int kt = 0; kt < KT; kt++)
#pragma unroll
        for (int j = 0; j < NSUB; j++)
            acc[j] = __builtin_amdgcn_mfma_f32_16x16x32_bf16(areg[kt], breg[kt * NSUB + j], acc[j], 0, 0, 0);

    const int m0 = mt * 64;
#pragma unroll
    for (int j = 0; j < NSUB; j++) {
        int f = (ns * NSUB + j) * 16 + mrow;
        float s = S[f];
        float t = T[f];
#pragma unroll
        for (int r = 0; r < 4; r++) {
            int row = m0 + wv * 16 + kb * 4 + r;
            if (row < M) {
                u16 val = f2u(fmaxf(acc[j][r] * s + t, 0.0f));
                if (NSLICE_OUT > 0)
                    C[((size_t)(f >> 5) * npad + row) * 32 + (f & 31)] = val;
                else
                    C[(size_t)row * N + f] = val;
            }
        }
    }
}

// ---------------- segmented pooling over sorted batch ----------------------
#define POOL_NC 64
__global__ __launch_bounds__(256) void pool_seg(
    const u16* __restrict__ h, const int* __restrict__ batch,
    float* __restrict__ psum, float* __restrict__ pmax,
    int* __restrict__ pcnt, int n) {
    int wid = (int)(((size_t)blockIdx.x * blockDim.x + threadIdx.x) >> 6);
    int lane = threadIdx.x & 63;
    int n0 = wid * POOL_NC;
    if (n0 >= n) return;
    int n1 = min(n0 + POOL_NC, n);

    float sum[4] = {0.f, 0.f, 0.f, 0.f};
    float mx[4] = {0.f, 0.f, 0.f, 0.f};
    int cnt = 0;
    int gcur = batch[n0];

    uint2 u_next = *(const uint2*)(h + (size_t)n0 * 256 + lane * 4);
    int g_next = gcur;

    for (int node = n0; node < n1; node++) {
        uint2 u = u_next;
        int g = g_next;
        if (node + 1 < n1) {
            u_next = *(const uint2*)(h + (size_t)(node + 1) * 256 + lane * 4);
            g_next = batch[node + 1];
        }
        if (g != gcur) {
#pragma unroll
            for (int c = 0; c < 4; c++) {
                atomicAdd(&psum[gcur * 256 + lane * 4 + c], sum[c]);
                atomicMax((int*)&pmax[gcur * 256 + lane * 4 + c], __float_as_int(mx[c]));
                sum[c] = 0.f; mx[c] = 0.f;
            }
            if (lane == 0) atomicAdd(&pcnt[gcur], cnt);
            cnt = 0;
            gcur = g;
        }
        float v0 = bf_lo(u.x), v1 = bf_hi(u.x), v2 = bf_lo(u.y), v3 = bf_hi(u.y);
        sum[0] += v0; sum[1] += v1; sum[2] += v2; sum[3] += v3;
        mx[0] = fmaxf(mx[0], v0); mx[1] = fmaxf(mx[1], v1);
        mx[2] = fmaxf(mx[2], v2); mx[3] = fmaxf(mx[3], v3);
        cnt++;
    }
#pragma unroll
    for (int c = 0; c < 4; c++) {
        atomicAdd(&psum[gcur * 256 + lane * 4 + c], sum[c]);
        atomicMax((int*)&pmax[gcur * 256 + lane * 4 + c], __float_as_int(mx[c]));
    }
    if (lane == 0) atomicAdd(&pcnt[gcur], cnt);
}

// ---------------- fully fused MLP head ----------------
__global__ __launch_bounds__(256) void mlp_fused(
    const float* __restrict__ psum, const float* __restrict__ pmax,
    const int* __restrict__ pcnt,
    const void* __restrict__ Wm1, const void* __restrict__ bm1,
    const void* __restrict__ Wm2, const void* __restrict__ bm2,
    const void* __restrict__ Wm3, const void* __restrict__ bm3,
    void* __restrict__ out, const int* __restrict__ flag) {
    __shared__ float a[512];
    __shared__ float h1[256];
    __shared__ float h2[128];
    int row = blockIdx.x;
    int tid = threadIdx.x;
    int isbf = *flag;
    float invc = 1.0f / (float)max(pcnt[row], 1);
    a[tid] = psum[row * 256 + tid] * invc;
    a[256 + tid] = pmax[row * 256 + tid];
    __syncthreads();
    {
        float acc = load_f(bm1, tid, isbf);
        if (isbf) {
            const bf16* w = (const bf16*)Wm1;
            for (int k = 0; k < 512; k++) acc += a[k] * b2f(w[k * 256 + tid]);
        } else {
            const float* w = (const float*)Wm1;
            for (int k = 0; k < 512; k++) acc += a[k] * w[k * 256 + tid];
        }
        h1[tid] = 0.5f * acc * (1.0f + erff(acc * 0.70710678118654752f));
    }
    __syncthreads();
    if (tid < 128) {
        float acc = load_f(bm2, tid, isbf);
        if (isbf) {
            const bf16* w = (const bf16*)Wm2;
            for (int k = 0; k < 256; k++) acc += h1[k] * b2f(w[k * 128 + tid]);
        } else {
            const float* w = (const float*)Wm2;
            for (int k = 0; k < 256; k++) acc += h1[k] * w[k * 128 + tid];
        }
        h2[tid] = 0.5f * acc * (1.0f + erff(acc * 0.70710678118654752f));
    }
    __syncthreads();
    if (tid < 6) {
        float acc = load_f(bm3, tid, isbf);
        if (isbf) {
            const bf16* w = (const bf16*)Wm3;
            for (int k = 0; k < 128; k++) acc += h2[k] * b2f(w[k * 6 + tid]);
        } else {
            const float* w = (const float*)Wm3;
            for (int k = 0; k < 128; k++) acc += h2[k] * w[k * 6 + tid];
        }
        if (isbf) ((bf16*)out)[row * 6 + tid] = __float2bfloat16(acc);
        else      ((float*)out)[row * 6 + tid] = acc;
    }
}

extern "C" void kernel_launch(void* const* d_in, const int* in_sizes, int n_in,
                              void* d_out, int out_size, void* d_ws, size_t ws_size,
                              hipStream_t stream) {
    const void* x     = d_in[0];
    const int*  ei    = (const int*)d_in[1];
    const int*  batch = (const int*)d_in[2];
    const void *W1 = d_in[3],  *b1 = d_in[4],  *g1 = d_in[5],  *be1 = d_in[6],  *m1 = d_in[7],  *v1 = d_in[8];
    const void *W2 = d_in[9],  *b2 = d_in[10], *g2 = d_in[11], *be2 = d_in[12], *m2 = d_in[13], *v2 = d_in[14];
    const void *W3 = d_in[15], *b3 = d_in[16], *g3 = d_in[17], *be3 = d_in[18], *m3 = d_in[19], *v3 = d_in[20];
    const void *Wm1 = d_in[21], *bm1 = d_in[22];
    const void *Wm2 = d_in[23], *bm2 = d_in[24];
    const void *Wm3 = d_in[25], *bm3 = d_in[26];

    const int n = in_sizes[0] / 64;     // 50000
    const int E = in_sizes[1] / 2;      // 800000
    const int* src = ei;
    const int* dst = ei + E;
    const int npad = (n + 63 + 64) & ~63;
    const int ntiles = (n + 63) / 64;
    const int ntp8 = (ntiles + 7) & ~7;
    const int cap = E + 8 * n;          // csrw capacity (elements)

    size_t off = 0;
    auto carve = [&](size_t bytes) {
        void* p = (char*)d_ws + off;
        off += (bytes + 255) & ~(size_t)255;
        return p;
    };
    int*      flag  = (int*)carve(4);
    int*      ovf   = (int*)carve(4);
    int*      bcnt  = (int*)carve(NBUCK * 4);
    int*      claim = (int*)carve(NBUCK * 4);
    float*    dis   = (float*)carve((size_t)n * 4);
    int*      deg_i = (int*)carve((size_t)n * 4);
    int*      curs  = (int*)carve((size_t)n * 4);
    uint4*    ninfo = (uint4*)carve((size_t)n * 16);
    unsigned* csrw  = (unsigned*)carve((size_t)cap * 4);
    u16*      xs    = (u16*)carve((size_t)npad * 64 * 2);
    u16*      Hs    = (u16*)carve((size_t)npad * 256 * 2);
    u16*      AG    = (u16*)carve((size_t)npad * 256 * 2);
    u16*      H     = (u16*)carve((size_t)npad * 256 * 2);
    u16*      W1r   = (u16*)carve((size_t)64 * 128 * 2);
    u16*      W2r   = (u16*)carve((size_t)128 * 256 * 2);
    u16*      W3r   = (u16*)carve((size_t)256 * 256 * 2);
    float* S1 = (float*)carve(128 * 4); float* T1 = (float*)carve(128 * 4);
    float* S2 = (float*)carve(256 * 4); float* T2 = (float*)carve(256 * 4);
    float* S3 = (float*)carve(256 * 4); float* T3 = (float*)carve(256 * 4);
    float* psum = (float*)carve((size_t)NGRAPH * 256 * 4);
    float* pmax = (float*)carve((size_t)NGRAPH * 256 * 4);
    int*   pcnt = (int*)carve((size_t)NGRAPH * 4);
    (void)ws_size; (void)n_in;

    const int BT = 256;

    const int nb_cvt = (n * 64 + 255) / 256;
    const int nb_init = (NGRAPH * 256 + 255) / 256;
    prep_all<<<nb_cvt + 32 + 128 + 256 + 3 + nb_init, BT, 0, stream>>>(
        x, W1, W2, W3,
        b1, g1, be1, m1, v1, b2, g2, be2, m2, v2, b3, g3, be3, m3, v3,
        xs, W1r, W2r, W3r, S1, T1, S2, T2, S3, T3,
        deg_i, ovf, bcnt, claim, psum, pmax, pcnt, n, npad, flag);

    count_deg_i<<<(E + BT - 1) / BT, BT, 0, stream>>>(dst, deg_i, E);
    hist_rows<<<(n + BT - 1) / BT, BT, 0, stream>>>(deg_i, dis, bcnt, n);
    node_scatter<<<(n + BT - 1) / BT, BT, 0, stream>>>(deg_i, bcnt, claim, ovf,
                                                       curs, csrw, ninfo, n, cap);
    edge_scatter<<<(E + BT - 1) / BT, BT, 0, stream>>>(src, dst, dis, curs, csrw, E);

    const int nb32 = (n + 31) / 32;     // agg: 32 nodes per block

    // layer 1: agg x (2 slices) -> GEMM 64->128 (+BN+ReLU), out 4-sliced
    csr_agg_s6<2><<<2 * nb32, 256, 0, stream>>>(ninfo, csrw, xs, AG, n, npad);
    mfma_gemm_dg<64, 128, 4, 4><<<2 * ntp8, 256, 0, stream>>>(AG, W1r, S1, T1, Hs, n, npad, ntiles);

    // layer 2: agg h (4 slices) -> GEMM 128->256 (+BN+ReLU), out 8-sliced
    csr_agg_s6<4><<<4 * nb32, 256, 0, stream>>>(ninfo, csrw, Hs, AG, n, npad);
    mfma_gemm_dg<128, 256, 4, 8><<<4 * ntp8, 256, 0, stream>>>(AG, W2r, S2, T2, Hs, n, npad, ntiles);

    // layer 3: agg h (8 slices) -> GEMM 256->256 (+BN+ReLU), out row-major
    csr_agg_s6<8><<<8 * nb32, 256, 0, stream>>>(ninfo, csrw, Hs, AG, n, npad);
    mfma_gemm_dg<256, 256, 2, 0><<<8 * ntp8, 256, 0, stream>>>(AG, W3r, S3, T3, H, n, npad, ntiles);

    // pooling + fused MLP head
    const int pool_waves = (n + POOL_NC - 1) / POOL_NC;
    pool_seg<<<(pool_waves * 64 + BT - 1) / BT, BT, 0, stream>>>(H, batch, psum, pmax, pcnt, n);
    mlp_fused<<<NGRAPH, 256, 0, stream>>>(psum, pmax, pcnt, Wm1, bm1, Wm2, bm2, Wm3, bm3, d_out, flag);
}

// Round 22
// 414.220 us; speedup vs baseline: 1.0153x; 1.0153x over previous
//
#include <hip/hip_runtime.h>
#include <hip/hip_bf16.h>
#include <hip/hip_fp16.h>

typedef __hip_bfloat16 bf16;
typedef unsigned short u16;
typedef short bfrag __attribute__((ext_vector_type(8)));   // 8 bf16 = 4 VGPRs
typedef float f32x4 __attribute__((ext_vector_type(4)));
typedef unsigned u32x2 __attribute__((ext_vector_type(2))); // native vec for nt-store

#define NGRAPH 512
#define BN_EPS 1e-5f
#define NBUCK 64

__device__ __forceinline__ float b2f(bf16 x) { return __bfloat162float(x); }
__device__ __forceinline__ float bf_lo(unsigned u) { return __uint_as_float(u << 16); }
__device__ __forceinline__ float bf_hi(unsigned u) { return __uint_as_float(u & 0xffff0000u); }
__device__ __forceinline__ u16 f2u(float v) {
    bf16 t = __float2bfloat16(v);
    u16 r; __builtin_memcpy(&r, &t, 2); return r;
}

__device__ __forceinline__ float load_f(const void* p, int i, int isbf16) {
    if (isbf16) {
        unsigned short u = ((const unsigned short*)p)[i];
        return __uint_as_float(((unsigned int)u) << 16);
    }
    return ((const float*)p)[i];
}

// ---------------- fused prep+init ----------------
__device__ __forceinline__ void repack_sec(const void* W, u16* out, int Kd, int Nd,
                                           int t, int isbf) {
    if (t >= Kd * Nd) return;
    int j = t & 7;
    int lane = (t >> 3) & 63;
    int tile = t >> 9;
    int NT = Nd / 16;
    int nt = tile % NT, kt = tile / NT;
    int k = kt * 32 + (lane >> 4) * 8 + j;
    int nn = nt * 16 + (lane & 15);
    out[t] = f2u(load_f(W, k * Nd + nn, isbf));
}

__device__ __forceinline__ void fold_one(const void* b, const void* g, const void* be,
                                         const void* m, const void* v,
                                         float* S, float* T, int f, int isbf) {
    float bb = load_f(b, f, isbf), gg = load_f(g, f, isbf);
    float bee = load_f(be, f, isbf), mm = load_f(m, f, isbf);
    float vv = load_f(v, f, isbf);
    float s = gg * rsqrtf(vv + BN_EPS);
    S[f] = s;
    T[f] = (bb - mm) * s + bee;
}

__global__ void prep_all(
    const void* __restrict__ x,
    const void* W1, const void* W2, const void* W3,
    const void* b1, const void* g1, const void* be1, const void* m1, const void* v1,
    const void* b2, const void* g2, const void* be2, const void* m2, const void* v2,
    const void* b3, const void* g3, const void* be3, const void* m3, const void* v3,
    u16* __restrict__ xs, u16* W1r, u16* W2r, u16* W3r,
    float* S1, float* T1, float* S2, float* T2, float* S3, float* T3,
    int* __restrict__ deg, int* __restrict__ ovf, int* __restrict__ bcnt,
    int* __restrict__ claim, float* __restrict__ psum, float* __restrict__ pmax,
    int* __restrict__ pcnt,
    int n, int npad, int* __restrict__ flag) {
    __shared__ int lflag;
    if (threadIdx.x < 64) {
        unsigned short u = ((const unsigned short*)x)[2 * threadIdx.x];
        float f = __uint_as_float(((unsigned int)u) << 16);
        int crazy = (!(fabsf(f) <= 1024.0f)) ? 1 : 0;
        unsigned long long m = __ballot(crazy);
        if (threadIdx.x == 0) lflag = (m == 0ULL) ? 1 : 0;
    }
    __syncthreads();
    const int isbf = lflag;
    const int bid = blockIdx.x;
    const int tid = threadIdx.x;
    if (bid == 0 && tid == 0) *flag = isbf;

    const int nb_cvt = (n * 64 + 255) / 256;
    if (bid < nb_cvt) {
        int i = bid * 256 + tid;
        if (i < n * 64) {
            int node = i >> 6, f = i & 63;
            xs[((size_t)(f >> 5) * npad + node) * 32 + (f & 31)] = f2u(load_f(x, i, isbf));
        }
        return;
    }
    int b2_ = bid - nb_cvt;
    if (b2_ < 32)  { repack_sec(W1, W1r, 64, 128, b2_ * 256 + tid, isbf); return; }
    b2_ -= 32;
    if (b2_ < 128) { repack_sec(W2, W2r, 128, 256, b2_ * 256 + tid, isbf); return; }
    b2_ -= 128;
    if (b2_ < 256) { repack_sec(W3, W3r, 256, 256, b2_ * 256 + tid, isbf); return; }
    b2_ -= 256;
    if (b2_ < 3) {
        int t = b2_ * 256 + tid;
        if (t < 128) fold_one(b1, g1, be1, m1, v1, S1, T1, t, isbf);
        else if (t < 384) fold_one(b2, g2, be2, m2, v2, S2, T2, t - 128, isbf);
        else if (t < 640) fold_one(b3, g3, be3, m3, v3, S3, T3, t - 384, isbf);
        return;
    }
    b2_ -= 3;
    {
        int i = b2_ * 256 + tid;
        if (i < n) deg[i] = 0;
        if (i < NGRAPH * 256) { psum[i] = 0.f; pmax[i] = 0.f; }
        if (i < NGRAPH) pcnt[i] = 0;
        if (i < NBUCK) { bcnt[i] = 0; claim[i] = 0; }
        if (i == 0) *ovf = 0;
    }
}

// Count degrees AND record each edge's rank within its dst (the atomic's
// return value is free) — removes the second atomic pass entirely.
__global__ void count_rank(const int* __restrict__ dst, int* __restrict__ deg,
                           int* __restrict__ erank, int e) {
    int i = blockIdx.x * blockDim.x + threadIdx.x;
    if (i < e) erank[i] = atomicAdd(&deg[dst[i]], 1);
}

// Histogram by dpad-bucket k=(deg+7)>>3 + dis. LDS hist (r9 lesson).
__global__ void hist_rows(const int* __restrict__ deg, float* __restrict__ dis,
                          int* __restrict__ bcnt, int n) {
    __shared__ int lh[NBUCK];
    int tid = threadIdx.x;
    if (tid < NBUCK) lh[tid] = 0;
    __syncthreads();
    int i = blockIdx.x * blockDim.x + tid;
    if (i < n) {
        int d = deg[i];
        dis[i] = rsqrtf((float)(d + 1));    // +1 self-loop
        atomicAdd(&lh[min((d + 7) >> 3, NBUCK - 1)], 1);
    }
    __syncthreads();
    if (tid < NBUCK) {
        int c = lh[tid];
        if (c) atomicAdd(&bcnt[tid], c);
    }
}

// Node scatter: sorted rank -> closed-form csrw start (csrw order matches
// ninfo processing order; r20: FETCH 61->34 MB). Writes nstart + pads + ninfo.
__global__ void node_scatter(const int* __restrict__ deg, const int* __restrict__ bcnt,
                             int* __restrict__ claim, int* __restrict__ ovf,
                             int* __restrict__ nstart, unsigned* __restrict__ csrw,
                             uint4* __restrict__ ninfo, int n, int cap) {
    __shared__ int lh[NBUCK];
    __shared__ int lbase[NBUCK];
    __shared__ int cpre[NBUCK];
    __shared__ int wpre[NBUCK];
    int tid = threadIdx.x;
    if (tid < NBUCK) lh[tid] = 0;
    if (tid == 64) {
        int ca = 0, wa = 0;
        for (int k = 0; k < NBUCK; k++) {
            cpre[k] = ca; wpre[k] = wa;
            ca += bcnt[k]; wa += bcnt[k] * 8 * k;
        }
    }
    __syncthreads();
    int i = blockIdx.x * blockDim.x + tid;
    int b = 0, lr = 0, d = 0;
    if (i < n) {
        d = deg[i];
        b = min((d + 7) >> 3, NBUCK - 1);
        lr = atomicAdd(&lh[b], 1);
    }
    __syncthreads();
    if (tid < NBUCK) {
        int c = lh[tid];
        lbase[tid] = c ? atomicAdd(&claim[tid], c) : 0;
    }
    __syncthreads();
    if (i >= n) return;
    int rank = lbase[b] + lr;
    int pos = cpre[b] + rank;
    int dpad = (d + 7) & ~7;
    int start;
    if (b < NBUCK - 1) {
        start = wpre[b] + rank * 8 * b;
    } else {
        start = cap - atomicAdd(ovf, dpad) - dpad;
    }
    nstart[i] = start;
    unsigned val = (unsigned)(i & 0xffff);   // pad: src=self, norm=+0
    for (int k = d; k < dpad; k++) csrw[start + k] = val;
    ninfo[pos] = make_uint4(i, start, d, 0);
}

// Pack {pos, payload} per edge — all reads sequential or L2-resident tables,
// write purely sequential (8B). No atomics.
__global__ void make_recs(const int* __restrict__ src, const int* __restrict__ dst,
                          const int* __restrict__ erank, const int* __restrict__ nstart,
                          const float* __restrict__ dis, uint2* __restrict__ rec, int e) {
    int i = blockIdx.x * blockDim.x + threadIdx.x;
    if (i >= e) return;
    int s = src[i], dt = dst[i];
    unsigned pos = (unsigned)(nstart[dt] + erank[i]);
    float nw = dis[s] * dis[dt];
    unsigned short h = __half_as_ushort(__float2half(nw));
    rec[i] = make_uint2(pos, (unsigned)(s & 0xffff) | ((unsigned)h << 16));
}

// XCD-owned scatter: blockIdx&7 selects the XCD; each XCD-group streams ALL
// records (L3-served) but stores only its own 1/8 pos-range -> every csrw
// line has a single L2 owner. r21: the atomic arrival-order scatter's random
// cross-XCD 4B stores false-shared lines -> 53 MB HBM WRITE, 50 us.
__global__ __launch_bounds__(256) void xcd_scatter(
    const uint2* __restrict__ rec, unsigned* __restrict__ csrw, int e, int cap) {
    int xcd = blockIdx.x & 7;
    int g = blockIdx.x >> 3;
    int ngroups = gridDim.x >> 3;
    unsigned lo = (unsigned)(((long long)cap * xcd) >> 3);
    unsigned hi = (unsigned)(((long long)cap * (xcd + 1)) >> 3);
    int stride = ngroups * 256;
    for (int i = g * 256 + threadIdx.x; i < e; i += stride) {
        uint2 r = rec[i];
        if (r.x >= lo && r.x < hi) csrw[r.x] = r.y;
    }
}

// ---------------- XCD-sliced CSR aggregation v6 (16-deep pipeline) ---------
template <int NSLICE>
__global__ __launch_bounds__(256) void csr_agg_s6(
    const uint4* __restrict__ ninfo, const unsigned* __restrict__ csrw,
    const u16* __restrict__ hs, u16* __restrict__ AG, int n, int npad) {
    constexpr int F = NSLICE * 32;
    int slice = blockIdx.x % NSLICE;
    int nb = blockIdx.x / NSLICE;
    int lane = threadIdx.x & 63;
    int wv = threadIdx.x >> 6;
    int sub = lane >> 3, ls = lane & 7;
    int oidx = nb * 32 + wv * 8 + sub;
    if (oidx >= n) return;
    uint4 nf = ninfo[oidx];
    int node = (int)nf.x;
    int start = (int)nf.y;
    int d = (int)nf.z;
    int dpad = (d + 7) & ~7;
    float dd = 1.0f / (float)(d + 1);
    const u16* __restrict__ base = hs + (size_t)slice * npad * 32;

    float a0, a1, a2, a3;
    {
        uint2 u = *(const uint2*)(base + (size_t)node * 32 + ls * 4);
        a0 = bf_lo(u.x) * dd; a1 = bf_hi(u.x) * dd;
        a2 = bf_lo(u.y) * dd; a3 = bf_hi(u.y) * dd;
    }

    const unsigned* __restrict__ ep = csrw + start;
    int k = 0;
    for (; k + 16 <= dpad; k += 16) {
        unsigned m[16];
#pragma unroll
        for (int j = 0; j < 16; j++) m[j] = ep[k + j];
        uint2 q[16];
#pragma unroll
        for (int j = 0; j < 16; j++) {
            int s = (int)(m[j] & 0xffffu);
            q[j] = *(const uint2*)(base + (size_t)s * 32 + ls * 4);
        }
#pragma unroll
        for (int j = 0; j < 16; j++) {
            float w = __half2float(__ushort_as_half((unsigned short)(m[j] >> 16)));
            a0 += w * bf_lo(q[j].x); a1 += w * bf_hi(q[j].x);
            a2 += w * bf_lo(q[j].y); a3 += w * bf_hi(q[j].y);
        }
    }
    if (k < dpad) {
        unsigned m[8];
#pragma unroll
        for (int j = 0; j < 8; j++) m[j] = ep[k + j];
        uint2 q[8];
#pragma unroll
        for (int j = 0; j < 8; j++) {
            int s = (int)(m[j] & 0xffffu);
            q[j] = *(const uint2*)(base + (size_t)s * 32 + ls * 4);
        }
#pragma unroll
        for (int j = 0; j < 8; j++) {
            float w = __half2float(__ushort_as_half((unsigned short)(m[j] >> 16)));
            a0 += w * bf_lo(q[j].x); a1 += w * bf_hi(q[j].x);
            a2 += w * bf_lo(q[j].y); a3 += w * bf_hi(q[j].y);
        }
    }
    u32x2 o;
    o.x = (unsigned)f2u(a0) | ((unsigned)f2u(a1) << 16);
    o.y = (unsigned)f2u(a2) | ((unsigned)f2u(a3) << 16);
    __builtin_nontemporal_store(o, (u32x2*)(AG + (size_t)node * F + slice * 32 + ls * 4));
}

// ---------------- LDS-free direct-gather MFMA GEMM + fused BN + ReLU -------
template <int K, int N, int NSUB, int NSLICE_OUT>
__global__ __launch_bounds__(256) void mfma_gemm_dg(
    const u16* __restrict__ A, const u16* __restrict__ Wrep,
    const float* __restrict__ S, const float* __restrict__ T,
    u16* __restrict__ C, int M, int npad, int ntiles) {
    constexpr int NT = N / 16;
    constexpr int KT = K / 32;
    constexpr int NSPLIT = NT / NSUB;
    int bid = blockIdx.x;
    int g = bid >> 3;
    int ns = g % NSPLIT;
    int mt = (bid & 7) + 8 * (g / NSPLIT);
    if (mt >= ntiles) return;
    const int tid = threadIdx.x;
    const int lane = tid & 63;
    const int wv = tid >> 6;
    const int mrow = lane & 15;
    const int kb = lane >> 4;

    bfrag breg[KT * NSUB];
#pragma unroll
    for (int kt = 0; kt < KT; kt++)
#pragma unroll
        for (int j = 0; j < NSUB; j++)
            breg[kt * NSUB + j] = *(const bfrag*)(Wrep +
                ((size_t)(kt * NT + ns * NSUB + j) * 64 + lane) * 8);

    const u16* __restrict__ arow = A + (size_t)(mt * 64 + wv * 16 + mrow) * K + kb * 8;
    bfrag areg[KT];
#pragma unroll
    for (int kt = 0; kt < KT; kt++)
        areg[kt] = *(const bfrag*)(arow + kt * 32);

    f32x4 acc[NSUB];
#pragma unroll
    for (int j = 0; j < NSUB; j++) acc[j] = (f32x4){0.f, 0.f, 0.f, 0.f};
#pragma unroll
    for (int kt = 0; kt < KT; kt++)
#pragma unroll
        for (int j = 0; j < NSUB; j++)
            acc[j] = __builtin_amdgcn_mfma_f32_16x16x32_bf16(areg[kt], breg[kt * NSUB + j], acc[j], 0, 0, 0);

    const int m0 = mt * 64;
#pragma unroll
    for (int j = 0; j < NSUB; j++) {
        int f = (ns * NSUB + j) * 16 + mrow;
        float s = S[f];
        float t = T[f];
#pragma unroll
        for (int r = 0; r < 4; r++) {
            int row = m0 + wv * 16 + kb * 4 + r;
            if (row < M) {
                u16 val = f2u(fmaxf(acc[j][r] * s + t, 0.0f));
                if (NSLICE_OUT > 0)
                    C[((size_t)(f >> 5) * npad + row) * 32 + (f & 31)] = val;
                else
                    C[(size_t)row * N + f] = val;
            }
        }
    }
}

// ---------------- segmented pooling over sorted batch ----------------------
#define POOL_NC 64
__global__ __launch_bounds__(256) void pool_seg(
    const u16* __restrict__ h, const int* __restrict__ batch,
    float* __restrict__ psum, float* __restrict__ pmax,
    int* __restrict__ pcnt, int n) {
    int wid = (int)(((size_t)blockIdx.x * blockDim.x + threadIdx.x) >> 6);
    int lane = threadIdx.x & 63;
    int n0 = wid * POOL_NC;
    if (n0 >= n) return;
    int n1 = min(n0 + POOL_NC, n);

    float sum[4] = {0.f, 0.f, 0.f, 0.f};
    float mx[4] = {0.f, 0.f, 0.f, 0.f};
    int cnt = 0;
    int gcur = batch[n0];

    uint2 u_next = *(const uint2*)(h + (size_t)n0 * 256 + lane * 4);
    int g_next = gcur;

    for (int node = n0; node < n1; node++) {
        uint2 u = u_next;
        int g = g_next;
        if (node + 1 < n1) {
            u_next = *(const uint2*)(h + (size_t)(node + 1) * 256 + lane * 4);
            g_next = batch[node + 1];
        }
        if (g != gcur) {
#pragma unroll
            for (int c = 0; c < 4; c++) {
                atomicAdd(&psum[gcur * 256 + lane * 4 + c], sum[c]);
                atomicMax((int*)&pmax[gcur * 256 + lane * 4 + c], __float_as_int(mx[c]));
                sum[c] = 0.f; mx[c] = 0.f;
            }
            if (lane == 0) atomicAdd(&pcnt[gcur], cnt);
            cnt = 0;
            gcur = g;
        }
        float v0 = bf_lo(u.x), v1 = bf_hi(u.x), v2 = bf_lo(u.y), v3 = bf_hi(u.y);
        sum[0] += v0; sum[1] += v1; sum[2] += v2; sum[3] += v3;
        mx[0] = fmaxf(mx[0], v0); mx[1] = fmaxf(mx[1], v1);
        mx[2] = fmaxf(mx[2], v2); mx[3] = fmaxf(mx[3], v3);
        cnt++;
    }
#pragma unroll
    for (int c = 0; c < 4; c++) {
        atomicAdd(&psum[gcur * 256 + lane * 4 + c], sum[c]);
        atomicMax((int*)&pmax[gcur * 256 + lane * 4 + c], __float_as_int(mx[c]));
    }
    if (lane == 0) atomicAdd(&pcnt[gcur], cnt);
}

// ---------------- fully fused MLP head ----------------
__global__ __launch_bounds__(256) void mlp_fused(
    const float* __restrict__ psum, const float* __restrict__ pmax,
    const int* __restrict__ pcnt,
    const void* __restrict__ Wm1, const void* __restrict__ bm1,
    const void* __restrict__ Wm2, const void* __restrict__ bm2,
    const void* __restrict__ Wm3, const void* __restrict__ bm3,
    void* __restrict__ out, const int* __restrict__ flag) {
    __shared__ float a[512];
    __shared__ float h1[256];
    __shared__ float h2[128];
    int row = blockIdx.x;
    int tid = threadIdx.x;
    int isbf = *flag;
    float invc = 1.0f / (float)max(pcnt[row], 1);
    a[tid] = psum[row * 256 + tid] * invc;
    a[256 + tid] = pmax[row * 256 + tid];
    __syncthreads();
    {
        float acc = load_f(bm1, tid, isbf);
        if (isbf) {
            const bf16* w = (const bf16*)Wm1;
            for (int k = 0; k < 512; k++) acc += a[k] * b2f(w[k * 256 + tid]);
        } else {
            const float* w = (const float*)Wm1;
            for (int k = 0; k < 512; k++) acc += a[k] * w[k * 256 + tid];
        }
        h1[tid] = 0.5f * acc * (1.0f + erff(acc * 0.70710678118654752f));
    }
    __syncthreads();
    if (tid < 128) {
        float acc = load_f(bm2, tid, isbf);
        if (isbf) {
            const bf16* w = (const bf16*)Wm2;
            for (int k = 0; k < 256; k++) acc += h1[k] * b2f(w[k * 128 + tid]);
        } else {
            const float* w = (const float*)Wm2;
            for (int k = 0; k < 256; k++) acc += h1[k] * w[k * 128 + tid];
        }
        h2[tid] = 0.5f * acc * (1.0f + erff(acc * 0.70710678118654752f));
    }
    __syncthreads();
    if (tid < 6) {
        float acc = load_f(bm3, tid, isbf);
        if (isbf) {
            const bf16* w = (const bf16*)Wm3;
            for (int k = 0; k < 128; k++) acc += h2[k] * b2f(w[k * 6 + tid]);
        } else {
            const float* w = (const float*)Wm3;
            for (int k = 0; k < 128; k++) acc += h2[k] * w[k * 6 + tid];
        }
        if (isbf) ((bf16*)out)[row * 6 + tid] = __float2bfloat16(acc);
        else      ((float*)out)[row * 6 + tid] = acc;
    }
}

extern "C" void kernel_launch(void* const* d_in, const int* in_sizes, int n_in,
                              void* d_out, int out_size, void* d_ws, size_t ws_size,
                              hipStream_t stream) {
    const void* x     = d_in[0];
    const int*  ei    = (const int*)d_in[1];
    const int*  batch = (const int*)d_in[2];
    const void *W1 = d_in[3],  *b1 = d_in[4],  *g1 = d_in[5],  *be1 = d_in[6],  *m1 = d_in[7],  *v1 = d_in[8];
    const void *W2 = d_in[9],  *b2 = d_in[10], *g2 = d_in[11], *be2 = d_in[12], *m2 = d_in[13], *v2 = d_in[14];
    const void *W3 = d_in[15], *b3 = d_in[16], *g3 = d_in[17], *be3 = d_in[18], *m3 = d_in[19], *v3 = d_in[20];
    const void *Wm1 = d_in[21], *bm1 = d_in[22];
    const void *Wm2 = d_in[23], *bm2 = d_in[24];
    const void *Wm3 = d_in[25], *bm3 = d_in[26];

    const int n = in_sizes[0] / 64;     // 50000
    const int E = in_sizes[1] / 2;      // 800000
    const int* src = ei;
    const int* dst = ei + E;
    const int npad = (n + 63 + 64) & ~63;
    const int ntiles = (n + 63) / 64;
    const int ntp8 = (ntiles + 7) & ~7;
    const int cap = E + 8 * n;          // csrw capacity (elements)

    size_t off = 0;
    auto carve = [&](size_t bytes) {
        void* p = (char*)d_ws + off;
        off += (bytes + 255) & ~(size_t)255;
        return p;
    };
    int*      flag  = (int*)carve(4);
    int*      ovf   = (int*)carve(4);
    int*      bcnt  = (int*)carve(NBUCK * 4);
    int*      claim = (int*)carve(NBUCK * 4);
    float*    dis   = (float*)carve((size_t)n * 4);
    int*      deg_i = (int*)carve((size_t)n * 4);
    int*      nstart= (int*)carve((size_t)n * 4);
    int*      erank = (int*)carve((size_t)E * 4);
    uint2*    rec   = (uint2*)carve((size_t)E * 8);
    uint4*    ninfo = (uint4*)carve((size_t)n * 16);
    unsigned* csrw  = (unsigned*)carve((size_t)cap * 4);
    u16*      xs    = (u16*)carve((size_t)npad * 64 * 2);
    u16*      Hs    = (u16*)carve((size_t)npad * 256 * 2);
    u16*      AG    = (u16*)carve((size_t)npad * 256 * 2);
    u16*      H     = (u16*)carve((size_t)npad * 256 * 2);
    u16*      W1r   = (u16*)carve((size_t)64 * 128 * 2);
    u16*      W2r   = (u16*)carve((size_t)128 * 256 * 2);
    u16*      W3r   = (u16*)carve((size_t)256 * 256 * 2);
    float* S1 = (float*)carve(128 * 4); float* T1 = (float*)carve(128 * 4);
    float* S2 = (float*)carve(256 * 4); float* T2 = (float*)carve(256 * 4);
    float* S3 = (float*)carve(256 * 4); float* T3 = (float*)carve(256 * 4);
    float* psum = (float*)carve((size_t)NGRAPH * 256 * 4);
    float* pmax = (float*)carve((size_t)NGRAPH * 256 * 4);
    int*   pcnt = (int*)carve((size_t)NGRAPH * 4);
    (void)ws_size; (void)n_in;

    const int BT = 256;

    const int nb_cvt = (n * 64 + 255) / 256;
    const int nb_init = (NGRAPH * 256 + 255) / 256;
    prep_all<<<nb_cvt + 32 + 128 + 256 + 3 + nb_init, BT, 0, stream>>>(
        x, W1, W2, W3,
        b1, g1, be1, m1, v1, b2, g2, be2, m2, v2, b3, g3, be3, m3, v3,
        xs, W1r, W2r, W3r, S1, T1, S2, T2, S3, T3,
        deg_i, ovf, bcnt, claim, psum, pmax, pcnt, n, npad, flag);

    count_rank<<<(E + BT - 1) / BT, BT, 0, stream>>>(dst, deg_i, erank, E);
    hist_rows<<<(n + BT - 1) / BT, BT, 0, stream>>>(deg_i, dis, bcnt, n);
    node_scatter<<<(n + BT - 1) / BT, BT, 0, stream>>>(deg_i, bcnt, claim, ovf,
                                                       nstart, csrw, ninfo, n, cap);
    make_recs<<<(E + BT - 1) / BT, BT, 0, stream>>>(src, dst, erank, nstart, dis, rec, E);
    xcd_scatter<<<8 * 64, BT, 0, stream>>>(rec, csrw, E, cap);

    const int nb32 = (n + 31) / 32;     // agg: 32 nodes per block

    // layer 1: agg x (2 slices) -> GEMM 64->128 (+BN+ReLU), out 4-sliced
    csr_agg_s6<2><<<2 * nb32, 256, 0, stream>>>(ninfo, csrw, xs, AG, n, npad);
    mfma_gemm_dg<64, 128, 4, 4><<<2 * ntp8, 256, 0, stream>>>(AG, W1r, S1, T1, Hs, n, npad, ntiles);

    // layer 2: agg h (4 slices) -> GEMM 128->256 (+BN+ReLU), out 8-sliced
    csr_agg_s6<4><<<4 * nb32, 256, 0, stream>>>(ninfo, csrw, Hs, AG, n, npad);
    mfma_gemm_dg<128, 256, 4, 8><<<4 * ntp8, 256, 0, stream>>>(AG, W2r, S2, T2, Hs, n, npad, ntiles);

    // layer 3: agg h (8 slices) -> GEMM 256->256 (+BN+ReLU), out row-major
    csr_agg_s6<8><<<8 * nb32, 256, 0, stream>>>(ninfo, csrw, Hs, AG, n, npad);
    mfma_gemm_dg<256, 256, 2, 0><<<8 * ntp8, 256, 0, stream>>>(AG, W3r, S3, T3, H, n, npad, ntiles);

    // pooling + fused MLP head
    const int pool_waves = (n + POOL_NC - 1) / POOL_NC;
    pool_seg<<<(pool_waves * 64 + BT - 1) / BT, BT, 0, stream>>>(H, batch, psum, pmax, pcnt, n);
    mlp_fused<<<NGRAPH, 256, 0, stream>>>(psum, pmax, pcnt, Wm1, bm1, Wm2, bm2, Wm3, bm3, d_out, flag);
}

// Round 23
// 412.774 us; speedup vs baseline: 1.0188x; 1.0035x over previous
//
#include <hip/hip_runtime.h>
#include <hip/hip_bf16.h>
#include <hip/hip_fp16.h>

typedef __hip_bfloat16 bf16;
typedef unsigned short u16;
typedef short bfrag __attribute__((ext_vector_type(8)));   // 8 bf16 = 4 VGPRs
typedef float f32x4 __attribute__((ext_vector_type(4)));
typedef float f32x2 __attribute__((ext_vector_type(2)));   // v_pk_fma_f32 target
typedef unsigned u32x2 __attribute__((ext_vector_type(2))); // native vec for nt-store

#define NGRAPH 512
#define BN_EPS 1e-5f
#define NBUCK 64

__device__ __forceinline__ float b2f(bf16 x) { return __bfloat162float(x); }
__device__ __forceinline__ float bf_lo(unsigned u) { return __uint_as_float(u << 16); }
__device__ __forceinline__ float bf_hi(unsigned u) { return __uint_as_float(u & 0xffff0000u); }
__device__ __forceinline__ u16 f2u(float v) {
    bf16 t = __float2bfloat16(v);
    u16 r; __builtin_memcpy(&r, &t, 2); return r;
}

__device__ __forceinline__ float load_f(const void* p, int i, int isbf16) {
    if (isbf16) {
        unsigned short u = ((const unsigned short*)p)[i];
        return __uint_as_float(((unsigned int)u) << 16);
    }
    return ((const float*)p)[i];
}

// ---------------- fused prep+init ----------------
__device__ __forceinline__ void repack_sec(const void* W, u16* out, int Kd, int Nd,
                                           int t, int isbf) {
    if (t >= Kd * Nd) return;
    int j = t & 7;
    int lane = (t >> 3) & 63;
    int tile = t >> 9;
    int NT = Nd / 16;
    int nt = tile % NT, kt = tile / NT;
    int k = kt * 32 + (lane >> 4) * 8 + j;
    int nn = nt * 16 + (lane & 15);
    out[t] = f2u(load_f(W, k * Nd + nn, isbf));
}

__device__ __forceinline__ void fold_one(const void* b, const void* g, const void* be,
                                         const void* m, const void* v,
                                         float* S, float* T, int f, int isbf) {
    float bb = load_f(b, f, isbf), gg = load_f(g, f, isbf);
    float bee = load_f(be, f, isbf), mm = load_f(m, f, isbf);
    float vv = load_f(v, f, isbf);
    float s = gg * rsqrtf(vv + BN_EPS);
    S[f] = s;
    T[f] = (bb - mm) * s + bee;
}

__global__ void prep_all(
    const void* __restrict__ x,
    const void* W1, const void* W2, const void* W3,
    const void* b1, const void* g1, const void* be1, const void* m1, const void* v1,
    const void* b2, const void* g2, const void* be2, const void* m2, const void* v2,
    const void* b3, const void* g3, const void* be3, const void* m3, const void* v3,
    u16* __restrict__ xs, u16* W1r, u16* W2r, u16* W3r,
    float* S1, float* T1, float* S2, float* T2, float* S3, float* T3,
    int* __restrict__ deg, int* __restrict__ ovf, int* __restrict__ bcnt,
    int* __restrict__ claim, float* __restrict__ psum, float* __restrict__ pmax,
    int* __restrict__ pcnt,
    int n, int npad, int* __restrict__ flag) {
    __shared__ int lflag;
    if (threadIdx.x < 64) {
        unsigned short u = ((const unsigned short*)x)[2 * threadIdx.x];
        float f = __uint_as_float(((unsigned int)u) << 16);
        int crazy = (!(fabsf(f) <= 1024.0f)) ? 1 : 0;
        unsigned long long m = __ballot(crazy);
        if (threadIdx.x == 0) lflag = (m == 0ULL) ? 1 : 0;
    }
    __syncthreads();
    const int isbf = lflag;
    const int bid = blockIdx.x;
    const int tid = threadIdx.x;
    if (bid == 0 && tid == 0) *flag = isbf;

    const int nb_cvt = (n * 64 + 255) / 256;
    if (bid < nb_cvt) {
        int i = bid * 256 + tid;
        if (i < n * 64) {
            int node = i >> 6, f = i & 63;
            xs[((size_t)(f >> 5) * npad + node) * 32 + (f & 31)] = f2u(load_f(x, i, isbf));
        }
        return;
    }
    int b2_ = bid - nb_cvt;
    if (b2_ < 32)  { repack_sec(W1, W1r, 64, 128, b2_ * 256 + tid, isbf); return; }
    b2_ -= 32;
    if (b2_ < 128) { repack_sec(W2, W2r, 128, 256, b2_ * 256 + tid, isbf); return; }
    b2_ -= 128;
    if (b2_ < 256) { repack_sec(W3, W3r, 256, 256, b2_ * 256 + tid, isbf); return; }
    b2_ -= 256;
    if (b2_ < 3) {
        int t = b2_ * 256 + tid;
        if (t < 128) fold_one(b1, g1, be1, m1, v1, S1, T1, t, isbf);
        else if (t < 384) fold_one(b2, g2, be2, m2, v2, S2, T2, t - 128, isbf);
        else if (t < 640) fold_one(b3, g3, be3, m3, v3, S3, T3, t - 384, isbf);
        return;
    }
    b2_ -= 3;
    {
        int i = b2_ * 256 + tid;
        if (i < n) deg[i] = 0;
        if (i < NGRAPH * 256) { psum[i] = 0.f; pmax[i] = 0.f; }
        if (i < NGRAPH) pcnt[i] = 0;
        if (i < NBUCK) { bcnt[i] = 0; claim[i] = 0; }
        if (i == 0) *ovf = 0;
    }
}

// Count degrees AND record each edge's rank within its dst.
__global__ void count_rank(const int* __restrict__ dst, int* __restrict__ deg,
                           int* __restrict__ erank, int e) {
    int i = blockIdx.x * blockDim.x + threadIdx.x;
    if (i < e) erank[i] = atomicAdd(&deg[dst[i]], 1);
}

// Histogram by dpad-bucket k=(deg+7)>>3 + dis. LDS hist (r9 lesson).
__global__ void hist_rows(const int* __restrict__ deg, float* __restrict__ dis,
                          int* __restrict__ bcnt, int n) {
    __shared__ int lh[NBUCK];
    int tid = threadIdx.x;
    if (tid < NBUCK) lh[tid] = 0;
    __syncthreads();
    int i = blockIdx.x * blockDim.x + tid;
    if (i < n) {
        int d = deg[i];
        dis[i] = rsqrtf((float)(d + 1));    // +1 self-loop
        atomicAdd(&lh[min((d + 7) >> 3, NBUCK - 1)], 1);
    }
    __syncthreads();
    if (tid < NBUCK) {
        int c = lh[tid];
        if (c) atomicAdd(&bcnt[tid], c);
    }
}

// Node scatter: sorted rank -> closed-form csrw start (csrw order matches
// ninfo processing order; r20: FETCH 61->34 MB). Writes nstart + pads + ninfo.
__global__ void node_scatter(const int* __restrict__ deg, const int* __restrict__ bcnt,
                             int* __restrict__ claim, int* __restrict__ ovf,
                             int* __restrict__ nstart, unsigned* __restrict__ csrw,
                             uint4* __restrict__ ninfo, int n, int cap) {
    __shared__ int lh[NBUCK];
    __shared__ int lbase[NBUCK];
    __shared__ int cpre[NBUCK];
    __shared__ int wpre[NBUCK];
    int tid = threadIdx.x;
    if (tid < NBUCK) lh[tid] = 0;
    if (tid == 64) {
        int ca = 0, wa = 0;
        for (int k = 0; k < NBUCK; k++) {
            cpre[k] = ca; wpre[k] = wa;
            ca += bcnt[k]; wa += bcnt[k] * 8 * k;
        }
    }
    __syncthreads();
    int i = blockIdx.x * blockDim.x + tid;
    int b = 0, lr = 0, d = 0;
    if (i < n) {
        d = deg[i];
        b = min((d + 7) >> 3, NBUCK - 1);
        lr = atomicAdd(&lh[b], 1);
    }
    __syncthreads();
    if (tid < NBUCK) {
        int c = lh[tid];
        lbase[tid] = c ? atomicAdd(&claim[tid], c) : 0;
    }
    __syncthreads();
    if (i >= n) return;
    int rank = lbase[b] + lr;
    int pos = cpre[b] + rank;
    int dpad = (d + 7) & ~7;
    int start;
    if (b < NBUCK - 1) {
        start = wpre[b] + rank * 8 * b;
    } else {
        start = cap - atomicAdd(ovf, dpad) - dpad;
    }
    nstart[i] = start;
    unsigned val = (unsigned)(i & 0xffff);   // pad: src=self, norm=+0
    for (int k = d; k < dpad; k++) csrw[start + k] = val;
    ninfo[pos] = make_uint4(i, start, d, 0);
}

// Pack {pos, payload} per edge — sequential writes, no atomics.
__global__ void make_recs(const int* __restrict__ src, const int* __restrict__ dst,
                          const int* __restrict__ erank, const int* __restrict__ nstart,
                          const float* __restrict__ dis, uint2* __restrict__ rec, int e) {
    int i = blockIdx.x * blockDim.x + threadIdx.x;
    if (i >= e) return;
    int s = src[i], dt = dst[i];
    unsigned pos = (unsigned)(nstart[dt] + erank[i]);
    float nw = dis[s] * dis[dt];
    unsigned short h = __half_as_ushort(__float2half(nw));
    rec[i] = make_uint2(pos, (unsigned)(s & 0xffff) | ((unsigned)h << 16));
}

// XCD-owned scatter (r22: kills cross-XCD false-sharing; WRITE 53 -> ~8 MB).
__global__ __launch_bounds__(256) void xcd_scatter(
    const uint2* __restrict__ rec, unsigned* __restrict__ csrw, int e, int cap) {
    int xcd = blockIdx.x & 7;
    int g = blockIdx.x >> 3;
    int ngroups = gridDim.x >> 3;
    unsigned lo = (unsigned)(((long long)cap * xcd) >> 3);
    unsigned hi = (unsigned)(((long long)cap * (xcd + 1)) >> 3);
    int stride = ngroups * 256;
    for (int i = g * 256 + threadIdx.x; i < e; i += stride) {
        uint2 r = rec[i];
        if (r.x >= lo && r.x < hi) csrw[r.x] = r.y;
    }
}

// ---------------- XCD-sliced CSR aggregation v7 ----------------------------
// 8-deep pipeline (r21's 16-deep: +0.8us but -8pt occupancy; revert) with
// f32x2 packed accumulators to halve FMA issue (v_pk_fma_f32).
template <int NSLICE>
__global__ __launch_bounds__(256) void csr_agg_s7(
    const uint4* __restrict__ ninfo, const unsigned* __restrict__ csrw,
    const u16* __restrict__ hs, u16* __restrict__ AG, int n, int npad) {
    constexpr int F = NSLICE * 32;
    int slice = blockIdx.x % NSLICE;
    int nb = blockIdx.x / NSLICE;
    int lane = threadIdx.x & 63;
    int wv = threadIdx.x >> 6;
    int sub = lane >> 3, ls = lane & 7;
    int oidx = nb * 32 + wv * 8 + sub;
    if (oidx >= n) return;
    uint4 nf = ninfo[oidx];
    int node = (int)nf.x;
    int start = (int)nf.y;
    int d = (int)nf.z;
    int dpad = (d + 7) & ~7;
    float dd = 1.0f / (float)(d + 1);
    const u16* __restrict__ base = hs + (size_t)slice * npad * 32;

    f32x2 acc01, acc23;
    {
        uint2 u = *(const uint2*)(base + (size_t)node * 32 + ls * 4);
        acc01 = (f32x2){bf_lo(u.x) * dd, bf_hi(u.x) * dd};
        acc23 = (f32x2){bf_lo(u.y) * dd, bf_hi(u.y) * dd};
    }

    const unsigned* __restrict__ ep = csrw + start;
    unsigned mc[8];
    if (dpad) {
#pragma unroll
        for (int j = 0; j < 8; j++) mc[j] = ep[j];
    }
    for (int k = 0; k < dpad; k += 8) {
        unsigned mn[8];
        if (k + 8 < dpad) {
#pragma unroll
            for (int j = 0; j < 8; j++) mn[j] = ep[k + 8 + j];
        }
        uint2 q[8];
#pragma unroll
        for (int j = 0; j < 8; j++) {
            int s = (int)(mc[j] & 0xffffu);
            q[j] = *(const uint2*)(base + (size_t)s * 32 + ls * 4);
        }
#pragma unroll
        for (int j = 0; j < 8; j++) {
            float w = __half2float(__ushort_as_half((unsigned short)(mc[j] >> 16)));
            f32x2 wv2 = (f32x2){w, w};
            acc01 += wv2 * (f32x2){bf_lo(q[j].x), bf_hi(q[j].x)};
            acc23 += wv2 * (f32x2){bf_lo(q[j].y), bf_hi(q[j].y)};
        }
#pragma unroll
        for (int j = 0; j < 8; j++) mc[j] = mn[j];
    }
    u32x2 o;
    o.x = (unsigned)f2u(acc01.x) | ((unsigned)f2u(acc01.y) << 16);
    o.y = (unsigned)f2u(acc23.x) | ((unsigned)f2u(acc23.y) << 16);
    __builtin_nontemporal_store(o, (u32x2*)(AG + (size_t)node * F + slice * 32 + ls * 4));
}

// ---------------- LDS-free direct-gather MFMA GEMM + fused BN + ReLU -------
template <int K, int N, int NSUB, int NSLICE_OUT>
__global__ __launch_bounds__(256) void mfma_gemm_dg(
    const u16* __restrict__ A, const u16* __restrict__ Wrep,
    const float* __restrict__ S, const float* __restrict__ T,
    u16* __restrict__ C, int M, int npad, int ntiles) {
    constexpr int NT = N / 16;
    constexpr int KT = K / 32;
    constexpr int NSPLIT = NT / NSUB;
    int bid = blockIdx.x;
    int g = bid >> 3;
    int ns = g % NSPLIT;
    int mt = (bid & 7) + 8 * (g / NSPLIT);
    if (mt >= ntiles) return;
    const int tid = threadIdx.x;
    const int lane = tid & 63;
    const int wv = tid >> 6;
    const int mrow = lane & 15;
    const int kb = lane >> 4;

    bfrag breg[KT * NSUB];
#pragma unroll
    for (int kt = 0; kt < KT; kt++)
#pragma unroll
        for (int j = 0; j < NSUB; j++)
            breg[kt * NSUB + j] = *(const bfrag*)(Wrep +
                ((size_t)(kt * NT + ns * NSUB + j) * 64 + lane) * 8);

    const u16* __restrict__ arow = A + (size_t)(mt * 64 + wv * 16 + mrow) * K + kb * 8;
    bfrag areg[KT];
#pragma unroll
    for (int kt = 0; kt < KT; kt++)
        areg[kt] = *(const bfrag*)(arow + kt * 32);

    f32x4 acc[NSUB];
#pragma unroll
    for (int j = 0; j < NSUB; j++) acc[j] = (f32x4){0.f, 0.f, 0.f, 0.f};
#pragma unroll
    for (int kt = 0; kt < KT; kt++)
#pragma unroll
        for (int j = 0; j < NSUB; j++)
            acc[j] = __builtin_amdgcn_mfma_f32_16x16x32_bf16(areg[kt], breg[kt * NSUB + j], acc[j], 0, 0, 0);

    const int m0 = mt * 64;
#pragma unroll
    for (int j = 0; j < NSUB; j++) {
        int f = (ns * NSUB + j) * 16 + mrow;
        float s = S[f];
        float t = T[f];
#pragma unroll
        for (int r = 0; r < 4; r++) {
            int row = m0 + wv * 16 + kb * 4 + r;
            if (row < M) {
                u16 val = f2u(fmaxf(acc[j][r] * s + t, 0.0f));
                if (NSLICE_OUT > 0)
                    C[((size_t)(f >> 5) * npad + row) * 32 + (f & 31)] = val;
                else
                    C[(size_t)row * N + f] = val;
            }
        }
    }
}

// ---------------- segmented pooling over sorted batch ----------------------
#define POOL_NC 64
__global__ __launch_bounds__(256) void pool_seg(
    const u16* __restrict__ h, const int* __restrict__ batch,
    float* __restrict__ psum, float* __restrict__ pmax,
    int* __restrict__ pcnt, int n) {
    int wid = (int)(((size_t)blockIdx.x * blockDim.x + threadIdx.x) >> 6);
    int lane = threadIdx.x & 63;
    int n0 = wid * POOL_NC;
    if (n0 >= n) return;
    int n1 = min(n0 + POOL_NC, n);

    float sum[4] = {0.f, 0.f, 0.f, 0.f};
    float mx[4] = {0.f, 0.f, 0.f, 0.f};
    int cnt = 0;
    int gcur = batch[n0];

    uint2 u_next = *(const uint2*)(h + (size_t)n0 * 256 + lane * 4);
    int g_next = gcur;

    for (int node = n0; node < n1; node++) {
        uint2 u = u_next;
        int g = g_next;
        if (node + 1 < n1) {
            u_next = *(const uint2*)(h + (size_t)(node + 1) * 256 + lane * 4);
            g_next = batch[node + 1];
        }
        if (g != gcur) {
#pragma unroll
            for (int c = 0; c < 4; c++) {
                atomicAdd(&psum[gcur * 256 + lane * 4 + c], sum[c]);
                atomicMax((int*)&pmax[gcur * 256 + lane * 4 + c], __float_as_int(mx[c]));
                sum[c] = 0.f; mx[c] = 0.f;
            }
            if (lane == 0) atomicAdd(&pcnt[gcur], cnt);
            cnt = 0;
            gcur = g;
        }
        float v0 = bf_lo(u.x), v1 = bf_hi(u.x), v2 = bf_lo(u.y), v3 = bf_hi(u.y);
        sum[0] += v0; sum[1] += v1; sum[2] += v2; sum[3] += v3;
        mx[0] = fmaxf(mx[0], v0); mx[1] = fmaxf(mx[1], v1);
        mx[2] = fmaxf(mx[2], v2); mx[3] = fmaxf(mx[3], v3);
        cnt++;
    }
#pragma unroll
    for (int c = 0; c < 4; c++) {
        atomicAdd(&psum[gcur * 256 + lane * 4 + c], sum[c]);
        atomicMax((int*)&pmax[gcur * 256 + lane * 4 + c], __float_as_int(mx[c]));
    }
    if (lane == 0) atomicAdd(&pcnt[gcur], cnt);
}

// ---------------- fully fused MLP head ----------------
__global__ __launch_bounds__(256) void mlp_fused(
    const float* __restrict__ psum, const float* __restrict__ pmax,
    const int* __restrict__ pcnt,
    const void* __restrict__ Wm1, const void* __restrict__ bm1,
    const void* __restrict__ Wm2, const void* __restrict__ bm2,
    const void* __restrict__ Wm3, const void* __restrict__ bm3,
    void* __restrict__ out, const int* __restrict__ flag) {
    __shared__ float a[512];
    __shared__ float h1[256];
    __shared__ float h2[128];
    int row = blockIdx.x;
    int tid = threadIdx.x;
    int isbf = *flag;
    float invc = 1.0f / (float)max(pcnt[row], 1);
    a[tid] = psum[row * 256 + tid] * invc;
    a[256 + tid] = pmax[row * 256 + tid];
    __syncthreads();
    {
        float acc = load_f(bm1, tid, isbf);
        if (isbf) {
            const bf16* w = (const bf16*)Wm1;
            for (int k = 0; k < 512; k++) acc += a[k] * b2f(w[k * 256 + tid]);
        } else {
            const float* w = (const float*)Wm1;
            for (int k = 0; k < 512; k++) acc += a[k] * w[k * 256 + tid];
        }
        h1[tid] = 0.5f * acc * (1.0f + erff(acc * 0.70710678118654752f));
    }
    __syncthreads();
    if (tid < 128) {
        float acc = load_f(bm2, tid, isbf);
        if (isbf) {
            const bf16* w = (const bf16*)Wm2;
            for (int k = 0; k < 256; k++) acc += h1[k] * b2f(w[k * 128 + tid]);
        } else {
            const float* w = (const float*)Wm2;
            for (int k = 0; k < 256; k++) acc += h1[k] * w[k * 128 + tid];
        }
        h2[tid] = 0.5f * acc * (1.0f + erff(acc * 0.70710678118654752f));
    }
    __syncthreads();
    if (tid < 6) {
        float acc = load_f(bm3, tid, isbf);
        if (isbf) {
            const bf16* w = (const bf16*)Wm3;
            for (int k = 0; k < 128; k++) acc += h2[k] * b2f(w[k * 6 + tid]);
        } else {
            const float* w = (const float*)Wm3;
            for (int k = 0; k < 128; k++) acc += h2[k] * w[k * 6 + tid];
        }
        if (isbf) ((bf16*)out)[row * 6 + tid] = __float2bfloat16(acc);
        else      ((float*)out)[row * 6 + tid] = acc;
    }
}

extern "C" void kernel_launch(void* const* d_in, const int* in_sizes, int n_in,
                              void* d_out, int out_size, void* d_ws, size_t ws_size,
                              hipStream_t stream) {
    const void* x     = d_in[0];
    const int*  ei    = (const int*)d_in[1];
    const int*  batch = (const int*)d_in[2];
    const void *W1 = d_in[3],  *b1 = d_in[4],  *g1 = d_in[5],  *be1 = d_in[6],  *m1 = d_in[7],  *v1 = d_in[8];
    const void *W2 = d_in[9],  *b2 = d_in[10], *g2 = d_in[11], *be2 = d_in[12], *m2 = d_in[13], *v2 = d_in[14];
    const void *W3 = d_in[15], *b3 = d_in[16], *g3 = d_in[17], *be3 = d_in[18], *m3 = d_in[19], *v3 = d_in[20];
    const void *Wm1 = d_in[21], *bm1 = d_in[22];
    const void *Wm2 = d_in[23], *bm2 = d_in[24];
    const void *Wm3 = d_in[25], *bm3 = d_in[26];

    const int n = in_sizes[0] / 64;     // 50000
    const int E = in_sizes[1] / 2;      // 800000
    const int* src = ei;
    const int* dst = ei + E;
    const int npad = (n + 63 + 64) & ~63;
    const int ntiles = (n + 63) / 64;
    const int ntp8 = (ntiles + 7) & ~7;
    const int cap = E + 8 * n;          // csrw capacity (elements)

    size_t off = 0;
    auto carve = [&](size_t bytes) {
        void* p = (char*)d_ws + off;
        off += (bytes + 255) & ~(size_t)255;
        return p;
    };
    int*      flag  = (int*)carve(4);
    int*      ovf   = (int*)carve(4);
    int*      bcnt  = (int*)carve(NBUCK * 4);
    int*      claim = (int*)carve(NBUCK * 4);
    float*    dis   = (float*)carve((size_t)n * 4);
    int*      deg_i = (int*)carve((size_t)n * 4);
    int*      nstart= (int*)carve((size_t)n * 4);
    int*      erank = (int*)carve((size_t)E * 4);
    uint2*    rec   = (uint2*)carve((size_t)E * 8);
    uint4*    ninfo = (uint4*)carve((size_t)n * 16);
    unsigned* csrw  = (unsigned*)carve((size_t)cap * 4);
    u16*      xs    = (u16*)carve((size_t)npad * 64 * 2);
    u16*      Hs    = (u16*)carve((size_t)npad * 256 * 2);
    u16*      AG    = (u16*)carve((size_t)npad * 256 * 2);
    u16*      H     = (u16*)carve((size_t)npad * 256 * 2);
    u16*      W1r   = (u16*)carve((size_t)64 * 128 * 2);
    u16*      W2r   = (u16*)carve((size_t)128 * 256 * 2);
    u16*      W3r   = (u16*)carve((size_t)256 * 256 * 2);
    float* S1 = (float*)carve(128 * 4); float* T1 = (float*)carve(128 * 4);
    float* S2 = (float*)carve(256 * 4); float* T2 = (float*)carve(256 * 4);
    float* S3 = (float*)carve(256 * 4); float* T3 = (float*)carve(256 * 4);
    float* psum = (float*)carve((size_t)NGRAPH * 256 * 4);
    float* pmax = (float*)carve((size_t)NGRAPH * 256 * 4);
    int*   pcnt = (int*)carve((size_t)NGRAPH * 4);
    (void)ws_size; (void)n_in;

    const int BT = 256;

    const int nb_cvt = (n * 64 + 255) / 256;
    const int nb_init = (NGRAPH * 256 + 255) / 256;
    prep_all<<<nb_cvt + 32 + 128 + 256 + 3 + nb_init, BT, 0, stream>>>(
        x, W1, W2, W3,
        b1, g1, be1, m1, v1, b2, g2, be2, m2, v2, b3, g3, be3, m3, v3,
        xs, W1r, W2r, W3r, S1, T1, S2, T2, S3, T3,
        deg_i, ovf, bcnt, claim, psum, pmax, pcnt, n, npad, flag);

    count_rank<<<(E + BT - 1) / BT, BT, 0, stream>>>(dst, deg_i, erank, E);
    hist_rows<<<(n + BT - 1) / BT, BT, 0, stream>>>(deg_i, dis, bcnt, n);
    node_scatter<<<(n + BT - 1) / BT, BT, 0, stream>>>(deg_i, bcnt, claim, ovf,
                                                       nstart, csrw, ninfo, n, cap);
    make_recs<<<(E + BT - 1) / BT, BT, 0, stream>>>(src, dst, erank, nstart, dis, rec, E);
    xcd_scatter<<<8 * 64, BT, 0, stream>>>(rec, csrw, E, cap);

    const int nb32 = (n + 31) / 32;     // agg: 32 nodes per block

    // layer 1: agg x (2 slices) -> GEMM 64->128 (+BN+ReLU), out 4-sliced
    csr_agg_s7<2><<<2 * nb32, 256, 0, stream>>>(ninfo, csrw, xs, AG, n, npad);
    mfma_gemm_dg<64, 128, 4, 4><<<2 * ntp8, 256, 0, stream>>>(AG, W1r, S1, T1, Hs, n, npad, ntiles);

    // layer 2: agg h (4 slices) -> GEMM 128->256 (+BN+ReLU), out 8-sliced
    csr_agg_s7<4><<<4 * nb32, 256, 0, stream>>>(ninfo, csrw, Hs, AG, n, npad);
    mfma_gemm_dg<128, 256, 4, 8><<<4 * ntp8, 256, 0, stream>>>(AG, W2r, S2, T2, Hs, n, npad, ntiles);

    // layer 3: agg h (8 slices) -> GEMM 256->256 (+BN+ReLU), out row-major
    csr_agg_s7<8><<<8 * nb32, 256, 0, stream>>>(ninfo, csrw, Hs, AG, n, npad);
    mfma_gemm_dg<256, 256, 2, 0><<<8 * ntp8, 256, 0, stream>>>(AG, W3r, S3, T3, H, n, npad, ntiles);

    // pooling + fused MLP head
    const int pool_waves = (n + POOL_NC - 1) / POOL_NC;
    pool_seg<<<(pool_waves * 64 + BT - 1) / BT, BT, 0, stream>>>(H, batch, psum, pmax, pcnt, n);
    mlp_fused<<<NGRAPH, 256, 0, stream>>>(psum, pmax, pcnt, Wm1, bm1, Wm2, bm2, Wm3, bm3, d_out, flag);
}